// Round 13
// baseline (362.099 us; speedup 1.0000x reference)
//
#include <hip/hip_runtime.h>

#define CAP 64

typedef _Float16 h8 __attribute__((ext_vector_type(8)));
typedef _Float16 h4 __attribute__((ext_vector_type(4)));
typedef float f32x4 __attribute__((ext_vector_type(4)));

__device__ __forceinline__ float lrelu(float x){ return x > 0.f ? x : 0.2f * x; }
__device__ __forceinline__ uint4 pack8(float4 a, float4 b){
  union { h8 h; uint4 u; } cv;
  cv.h = (h8){ (_Float16)a.x, (_Float16)a.y, (_Float16)a.z, (_Float16)a.w,
               (_Float16)b.x, (_Float16)b.y, (_Float16)b.z, (_Float16)b.w };
  return cv.u;
}
__device__ __forceinline__ void h8tof(uint4 u, float* f){
  union { uint4 u; h8 h; } cv; cv.u = u;
  #pragma unroll
  for (int i = 0; i < 8; ++i) f[i] = (float)cv.h[i];
}
// broadcast srcs[j] across the 16-lane group (j uniform within group)
__device__ __forceinline__ int bcast4(const int* s, int j, int gbase){
  int q = j >> 4;
  int sel = s[0];
  sel = (q == 1) ? s[1] : sel;
  sel = (q == 2) ? s[2] : sel;
  sel = (q == 3) ? s[3] : sel;
  return __shfl(sel, (j & 15) + gbase);
}

// ---------------- bucket build (counts + fixed-cap adjacency) ----------------
__global__ void build_kernel(const int* __restrict__ ei, int* __restrict__ cnt,
                             int* __restrict__ col2, int e_orig, int etot){
  int i = blockIdx.x * blockDim.x + threadIdx.x;
  if (i >= etot) return;
  int src, dst;
  if (i < e_orig){ src = ei[i]; dst = ei[e_orig + i]; }
  else { src = i - e_orig; dst = src; }           // self loops
  int pos = atomicAdd(&cnt[dst], 1);
  if (pos < CAP) col2[(size_t)dst * CAP + pos] = src;
}

// W pack: B0h[256x256] = [Wl0; Wr0], B1h[256x128] = [Wl1; Wr1]
__global__ void convw_kernel(const float* __restrict__ Wl0, const float* __restrict__ Wr0,
                             const float* __restrict__ Wl1, const float* __restrict__ Wr1,
                             _Float16* __restrict__ B0h, _Float16* __restrict__ B1h){
  int t = blockIdx.x * blockDim.x + threadIdx.x;   // float4 units, 24576 total
  const float* s; _Float16* d; int off;
  if (t < 8192)      { s = Wl0; d = B0h;          off = t; }
  else if (t < 16384){ s = Wr0; d = B0h + 32768;  off = t - 8192; }
  else if (t < 20480){ s = Wl1; d = B1h;          off = t - 16384; }
  else               { s = Wr1; d = B1h + 16384;  off = t - 20480; }
  float4 f = ((const float4*)s)[off];
  h4 h = { (_Float16)f.x, (_Float16)f.y, (_Float16)f.z, (_Float16)f.w };
  *(h4*)(d + 4 * (size_t)off) = h;
}

// ---------------- f16 MFMA GEMM, tile 64 rows x 128 cols ---------------------
// grid (2, 782): column-half in blockIdx.x so A-sharing blocks are adjacent
// (L2 reuse of A). A read as f32 (layer 0, fused convert) or f16 (layer 1).
// 4 waves: wave wx -> cols wx*32..+31 (4x2 MFMA tiles of 16x16x32_f16),
// BK=64, register-prefetch pipeline. Epilogue restages f16 C tile in LDS.
__global__ __launch_bounds__(256) void gemm_mfma(
    const float* __restrict__ A32, const _Float16* __restrict__ A16,
    const _Float16* __restrict__ Bw, _Float16* __restrict__ C, int n, int K)
{
  __shared__ __align__(16) char smem[27648];
  _Float16 (*Asm)[72] = (_Float16(*)[72])smem;            // 64 x 72
  _Float16 (*Bsm)[72] = (_Float16(*)[72])(smem + 9216);   // 128 x 72

  const int tid  = threadIdx.x;
  const int lane = tid & 63;
  const int wx   = tid >> 6;
  const int r0   = blockIdx.y * 64;
  const int cb   = blockIdx.x * 128;
  const int m16  = lane & 15, quad = lane >> 4;

  f32x4 acc[4][2];
  #pragma unroll
  for (int i = 0; i < 4; ++i)
    #pragma unroll
    for (int j = 0; j < 2; ++j)
      acc[i][j] = (f32x4){0.f, 0.f, 0.f, 0.f};

  const int srow = tid >> 2;        // 0..63
  const int kq   = (tid & 3) << 4;  // 0,16,32,48

  uint4 ra[2], rb[2][2];
  const uint4 z = {0u, 0u, 0u, 0u};

  if (r0 + srow < n){
    if (A32){
      const float* p = A32 + (size_t)(r0 + srow) * K + kq;
      ra[0] = pack8(*(const float4*)(p),     *(const float4*)(p + 4));
      ra[1] = pack8(*(const float4*)(p + 8), *(const float4*)(p + 12));
    } else {
      const _Float16* p = A16 + (size_t)(r0 + srow) * K + kq;
      ra[0] = *(const uint4*)(p);
      ra[1] = *(const uint4*)(p + 8);
    }
  } else { ra[0] = z; ra[1] = z; }
  #pragma unroll
  for (int v = 0; v < 2; ++v){
    const _Float16* p = Bw + (size_t)(cb + v * 64 + srow) * K + kq;
    rb[v][0] = *(const uint4*)(p);
    rb[v][1] = *(const uint4*)(p + 8);
  }

  const int nt = K >> 6;
  for (int t = 0; t < nt; ++t){
    *(uint4*)&Asm[srow][kq]     = ra[0];
    *(uint4*)&Asm[srow][kq + 8] = ra[1];
    #pragma unroll
    for (int v = 0; v < 2; ++v){
      *(uint4*)&Bsm[v * 64 + srow][kq]     = rb[v][0];
      *(uint4*)&Bsm[v * 64 + srow][kq + 8] = rb[v][1];
    }
    __syncthreads();
    if (t + 1 < nt){
      int kt = (t + 1) << 6;
      if (r0 + srow < n){
        if (A32){
          const float* p = A32 + (size_t)(r0 + srow) * K + kt + kq;
          ra[0] = pack8(*(const float4*)(p),     *(const float4*)(p + 4));
          ra[1] = pack8(*(const float4*)(p + 8), *(const float4*)(p + 12));
        } else {
          const _Float16* p = A16 + (size_t)(r0 + srow) * K + kt + kq;
          ra[0] = *(const uint4*)(p);
          ra[1] = *(const uint4*)(p + 8);
        }
      }
      #pragma unroll
      for (int v = 0; v < 2; ++v){
        const _Float16* p = Bw + (size_t)(cb + v * 64 + srow) * K + kt + kq;
        rb[v][0] = *(const uint4*)(p);
        rb[v][1] = *(const uint4*)(p + 8);
      }
    }
    #pragma unroll
    for (int ks = 0; ks < 2; ++ks){
      const int k0 = ks * 32 + quad * 8;
      h8 a[4], b[2];
      #pragma unroll
      for (int i = 0; i < 4; ++i)
        a[i] = *(const h8*)&Asm[i * 16 + m16][k0];
      #pragma unroll
      for (int j = 0; j < 2; ++j)
        b[j] = *(const h8*)&Bsm[wx * 32 + j * 16 + m16][k0];
      #pragma unroll
      for (int i = 0; i < 4; ++i)
        #pragma unroll
        for (int j = 0; j < 2; ++j)
          acc[i][j] = __builtin_amdgcn_mfma_f32_16x16x32_f16(a[i], b[j], acc[i][j], 0, 0, 0);
    }
    __syncthreads();
  }

  _Float16* Csm = (_Float16*)smem;
  #pragma unroll
  for (int i = 0; i < 4; ++i)
    #pragma unroll
    for (int r = 0; r < 4; ++r){
      int lrow = i * 16 + quad * 4 + r;
      _Float16* cp = Csm + lrow * 136 + wx * 32 + m16;
      #pragma unroll
      for (int j = 0; j < 2; ++j)
        cp[j * 16] = (_Float16)acc[i][j][r];
    }
  __syncthreads();
  #pragma unroll
  for (int v = 0; v < 4; ++v){
    int idx = v * 256 + tid;            // 1024 chunks of 8 f16
    int row = idx >> 4, cx = (idx & 15) * 8;
    if (r0 + row < n)
      *(uint4*)(C + (size_t)(r0 + row) * 256 + cb + cx)
        = *(const uint4*)(Csm + row * 136 + cx);
  }
}

// ---------------- GATv2 aggregation: 16-lane group per node, 8 ch/lane -------
// 2-level shfl_xor butterfly over 4-lane head groups; one uint4 (16 B) gather
// per lane per edge; depth-2 rotating prefetch; no LDS, no barriers.
__global__ __launch_bounds__(256) void agg_wave(
    const _Float16* __restrict__ XLR, const int* __restrict__ col2,
    const int* __restrict__ cnt, const float* __restrict__ att,
    const float* __restrict__ bias, _Float16* __restrict__ H16, int n)
{
  const int lane  = threadIdx.x & 63;
  const int g     = lane >> 4;          // group within wave (0..3)
  const int ll    = lane & 15;
  const int gbase = g << 4;
  const int nl    = ((threadIdx.x >> 6) << 2) + g;   // 0..15
  const int node  = blockIdx.x * 16 + nl;
  if (node >= n) return;
  int deg = cnt[node]; if (deg > CAP) deg = CAP;
  const int c0 = 8 * ll;

  float xr[8], av[8];
  h8tof(*(const uint4*)(XLR + (size_t)node * 256 + 128 + c0), xr);
  #pragma unroll
  for (int i = 0; i < 8; ++i) av[i] = att[c0 + i];

  int s[4];
  #pragma unroll
  for (int q = 0; q < 4; ++q)
    s[q] = (ll + 16 * q < deg) ? col2[(size_t)node * CAP + ll + 16 * q] : 0;

  float l = 0.f, accv[8];
  #pragma unroll
  for (int i = 0; i < 8; ++i) accv[i] = 0.f;

  int e0 = bcast4(s, 0, gbase);
  int j1 = (1 < deg) ? 1 : 0;
  int e1 = bcast4(s, j1, gbase);
  uint4 xa = *(const uint4*)(XLR + (size_t)e0 * 256 + c0);
  uint4 xb = *(const uint4*)(XLR + (size_t)e1 * 256 + c0);

  for (int j = 0; j < deg; ++j){
    float cur[8]; h8tof(xa, cur);
    int jn = (j + 2 < deg) ? j + 2 : 0;
    int sn = bcast4(s, jn, gbase);
    xa = xb;
    xb = *(const uint4*)(XLR + (size_t)sn * 256 + c0);
    float p = 0.f;
    #pragma unroll
    for (int i = 0; i < 8; ++i) p += lrelu(cur[i] + xr[i]) * av[i];
    p += __shfl_xor(p, 1);
    p += __shfl_xor(p, 2);                 // 4-lane head logit, all lanes
    float w = __expf(p);
    l += w;
    #pragma unroll
    for (int i = 0; i < 8; ++i) accv[i] += w * cur[i];
  }
  float inv = 1.f / l;
  union { h8 h; uint4 u; } o;
  #pragma unroll
  for (int i = 0; i < 8; ++i)
    o.h[i] = (_Float16)(accv[i] * inv + bias[c0 + i]);
  *(uint4*)(H16 + (size_t)node * 128 + c0) = o.u;
}

// ---------------- layer-1 aggregation fused with down_proj -------------------
// 16-lane groups (block covers 16 nodes); h staged f32 in LDS; then each
// thread computes 2 (node, o) dot products against LDS-staged dW.
__global__ __launch_bounds__(256) void agg_down(
    const _Float16* __restrict__ XLR, const int* __restrict__ col2,
    const int* __restrict__ cnt, const float* __restrict__ att,
    const float* __restrict__ bias, const float* __restrict__ dW,
    const float* __restrict__ db, float* __restrict__ out, int n)
{
  __shared__ float dwb[32][129];
  __shared__ float hsm[16][128];
  for (int i = threadIdx.x; i < 32 * 128; i += 256)
    dwb[i >> 7][i & 127] = dW[i];

  const int lane  = threadIdx.x & 63;
  const int g     = lane >> 4;
  const int ll    = lane & 15;
  const int gbase = g << 4;
  const int nl    = ((threadIdx.x >> 6) << 2) + g;   // 0..15
  const int node  = blockIdx.x * 16 + nl;
  const bool valid = node < n;
  int deg = 0;
  if (valid){ deg = cnt[node]; if (deg > CAP) deg = CAP; }
  const int c0 = 8 * ll;

  float xr[8], av[8];
  #pragma unroll
  for (int i = 0; i < 8; ++i) xr[i] = 0.f;
  if (valid) h8tof(*(const uint4*)(XLR + (size_t)node * 256 + 128 + c0), xr);
  #pragma unroll
  for (int i = 0; i < 8; ++i) av[i] = att[c0 + i];

  int s[4];
  #pragma unroll
  for (int q = 0; q < 4; ++q)
    s[q] = (valid && ll + 16 * q < deg) ? col2[(size_t)node * CAP + ll + 16 * q] : 0;

  float l = 0.f, accv[8];
  #pragma unroll
  for (int i = 0; i < 8; ++i) accv[i] = 0.f;

  int e0 = bcast4(s, 0, gbase);
  int j1 = (1 < deg) ? 1 : 0;
  int e1 = bcast4(s, j1, gbase);
  uint4 xa = *(const uint4*)(XLR + (size_t)e0 * 256 + c0);
  uint4 xb = *(const uint4*)(XLR + (size_t)e1 * 256 + c0);

  for (int j = 0; j < deg; ++j){
    float cur[8]; h8tof(xa, cur);
    int jn = (j + 2 < deg) ? j + 2 : 0;
    int sn = bcast4(s, jn, gbase);
    xa = xb;
    xb = *(const uint4*)(XLR + (size_t)sn * 256 + c0);
    float p = 0.f;
    #pragma unroll
    for (int i = 0; i < 8; ++i) p += lrelu(cur[i] + xr[i]) * av[i];
    p += __shfl_xor(p, 1);
    p += __shfl_xor(p, 2);
    float w = __expf(p);
    l += w;
    #pragma unroll
    for (int i = 0; i < 8; ++i) accv[i] += w * cur[i];
  }
  {
    float inv = (deg > 0) ? 1.f / l : 0.f;
    #pragma unroll
    for (int i = 0; i < 8; ++i)
      hsm[nl][c0 + i] = accv[i] * inv + bias[c0 + i];
  }
  __syncthreads();

  // ---- down phase: 512 outputs over 256 threads (2 each) ----
  const int o = threadIdx.x & 31;
  #pragma unroll
  for (int h2 = 0; h2 < 2; ++h2){
    int nl2 = (threadIdx.x >> 5) + h2 * 8;
    int node2 = blockIdx.x * 16 + nl2;
    float sum = 0.f;
    #pragma unroll 8
    for (int k = 0; k < 128; ++k)
      sum += hsm[nl2][k] * dwb[o][k];
    if (node2 < n)
      out[(size_t)node2 * 32 + o] = sum + db[o];
  }
}

extern "C" void kernel_launch(void* const* d_in, const int* in_sizes, int n_in,
                              void* d_out, int out_size, void* d_ws, size_t ws_size,
                              hipStream_t stream) {
  const float* x     = (const float*)d_in[0];
  const int*   ei    = (const int*)  d_in[1];
  const float* Wl0   = (const float*)d_in[2];
  const float* Wr0   = (const float*)d_in[3];
  const float* att0  = (const float*)d_in[4];
  const float* b0    = (const float*)d_in[5];
  const float* Wl1   = (const float*)d_in[6];
  const float* Wr1   = (const float*)d_in[7];
  const float* att1  = (const float*)d_in[8];
  const float* b1    = (const float*)d_in[9];
  const float* dW    = (const float*)d_in[10];
  const float* db    = (const float*)d_in[11];
  float* out = (float*)d_out;

  const int n    = in_sizes[0] / 256;      // 50000
  const int e    = in_sizes[1] / 2;        // 800000
  const int etot = e + n;

  // workspace layout
  _Float16* XLR16 = (_Float16*)d_ws;                    // n*256 f16
  _Float16* H16   = XLR16 + (size_t)n * 256;            // n*128 f16
  int* col2 = (int*)(H16 + (size_t)n * 128);            // n*CAP
  int* cnt  = col2 + (size_t)n * CAP;                   // n
  _Float16* B0h = (_Float16*)(cnt + ((n + 3) & ~3));    // 256*256 f16
  _Float16* B1h = B0h + 65536;                          // 256*128 f16

  (void)hipMemsetAsync(cnt, 0, (size_t)n * sizeof(int), stream);
  build_kernel<<<(etot + 255) / 256, 256, 0, stream>>>(ei, cnt, col2, e, etot);
  convw_kernel<<<96, 256, 0, stream>>>(Wl0, Wr0, Wl1, Wr1, B0h, B1h);

  dim3 ggrid(2, (n + 63) / 64);
  // layer 0 (A = x in f32, fused convert)
  gemm_mfma<<<ggrid, 256, 0, stream>>>(x, nullptr, B0h, XLR16, n, 256);
  agg_wave<<<(n + 15) / 16, 256, 0, stream>>>(XLR16, col2, cnt, att0, b0, H16, n);
  // layer 1 (A = H16 in f16)
  gemm_mfma<<<ggrid, 256, 0, stream>>>(nullptr, H16, B1h, XLR16, n, 128);
  // layer-1 agg + down proj fused
  agg_down<<<(n + 15) / 16, 256, 0, stream>>>(XLR16, col2, cnt, att1, b1, dW, db, out, n);
}

// Round 14
// 343.611 us; speedup vs baseline: 1.0538x; 1.0538x over previous
//
#include <hip/hip_runtime.h>

#define CAP 64

typedef _Float16 h8 __attribute__((ext_vector_type(8)));
typedef _Float16 h4 __attribute__((ext_vector_type(4)));
typedef float f32x4 __attribute__((ext_vector_type(4)));

__device__ __forceinline__ float lrelu(float x){ return x > 0.f ? x : 0.2f * x; }
__device__ __forceinline__ uint4 pack8(float4 a, float4 b){
  union { h8 h; uint4 u; } cv;
  cv.h = (h8){ (_Float16)a.x, (_Float16)a.y, (_Float16)a.z, (_Float16)a.w,
               (_Float16)b.x, (_Float16)b.y, (_Float16)b.z, (_Float16)b.w };
  return cv.u;
}
__device__ __forceinline__ void h8tof(uint4 u, float* f){
  union { uint4 u; h8 h; } cv; cv.u = u;
  #pragma unroll
  for (int i = 0; i < 8; ++i) f[i] = (float)cv.h[i];
}
// broadcast srcs[j] across the 16-lane group (j uniform within group)
__device__ __forceinline__ int bcast4(const int* s, int j, int gbase){
  int q = j >> 4;
  int sel = s[0];
  sel = (q == 1) ? s[1] : sel;
  sel = (q == 2) ? s[2] : sel;
  sel = (q == 3) ? s[3] : sel;
  return __shfl(sel, (j & 15) + gbase);
}

// ---------------- bucket build (counts + fixed-cap adjacency) ----------------
__global__ void build_kernel(const int* __restrict__ ei, int* __restrict__ cnt,
                             int* __restrict__ col2, int e_orig, int etot){
  int i = blockIdx.x * blockDim.x + threadIdx.x;
  if (i >= etot) return;
  int src, dst;
  if (i < e_orig){ src = ei[i]; dst = ei[e_orig + i]; }
  else { src = i - e_orig; dst = src; }           // self loops
  int pos = atomicAdd(&cnt[dst], 1);
  if (pos < CAP) col2[(size_t)dst * CAP + pos] = src;
}

// W pack: B0h[256x256] = [Wl0; Wr0], B1h[256x128] = [Wl1; Wr1]
__global__ void convw_kernel(const float* __restrict__ Wl0, const float* __restrict__ Wr0,
                             const float* __restrict__ Wl1, const float* __restrict__ Wr1,
                             _Float16* __restrict__ B0h, _Float16* __restrict__ B1h){
  int t = blockIdx.x * blockDim.x + threadIdx.x;   // float4 units, 24576 total
  const float* s; _Float16* d; int off;
  if (t < 8192)      { s = Wl0; d = B0h;          off = t; }
  else if (t < 16384){ s = Wr0; d = B0h + 32768;  off = t - 8192; }
  else if (t < 20480){ s = Wl1; d = B1h;          off = t - 16384; }
  else               { s = Wr1; d = B1h + 16384;  off = t - 20480; }
  float4 f = ((const float4*)s)[off];
  h4 h = { (_Float16)f.x, (_Float16)f.y, (_Float16)f.z, (_Float16)f.w };
  *(h4*)(d + 4 * (size_t)off) = h;
}

// ---------------- f16 MFMA GEMM, tile 64 rows x 128 cols ---------------------
// grid (2, 782): column-half in blockIdx.x so A-sharing blocks are adjacent
// (L2 reuse of A). A read as f32 (layer 0, fused convert) or f16 (layer 1).
// 4 waves: wave wx -> cols wx*32..+31 (4x2 MFMA tiles of 16x16x32_f16),
// BK=64, register-prefetch pipeline. Epilogue restages f16 C tile in LDS.
__global__ __launch_bounds__(256) void gemm_mfma(
    const float* __restrict__ A32, const _Float16* __restrict__ A16,
    const _Float16* __restrict__ Bw, _Float16* __restrict__ C, int n, int K)
{
  __shared__ __align__(16) char smem[27648];
  _Float16 (*Asm)[72] = (_Float16(*)[72])smem;            // 64 x 72
  _Float16 (*Bsm)[72] = (_Float16(*)[72])(smem + 9216);   // 128 x 72

  const int tid  = threadIdx.x;
  const int lane = tid & 63;
  const int wx   = tid >> 6;
  const int r0   = blockIdx.y * 64;
  const int cb   = blockIdx.x * 128;
  const int m16  = lane & 15, quad = lane >> 4;

  f32x4 acc[4][2];
  #pragma unroll
  for (int i = 0; i < 4; ++i)
    #pragma unroll
    for (int j = 0; j < 2; ++j)
      acc[i][j] = (f32x4){0.f, 0.f, 0.f, 0.f};

  const int srow = tid >> 2;        // 0..63
  const int kq   = (tid & 3) << 4;  // 0,16,32,48

  uint4 ra[2], rb[2][2];
  const uint4 z = {0u, 0u, 0u, 0u};

  if (r0 + srow < n){
    if (A32){
      const float* p = A32 + (size_t)(r0 + srow) * K + kq;
      ra[0] = pack8(*(const float4*)(p),     *(const float4*)(p + 4));
      ra[1] = pack8(*(const float4*)(p + 8), *(const float4*)(p + 12));
    } else {
      const _Float16* p = A16 + (size_t)(r0 + srow) * K + kq;
      ra[0] = *(const uint4*)(p);
      ra[1] = *(const uint4*)(p + 8);
    }
  } else { ra[0] = z; ra[1] = z; }
  #pragma unroll
  for (int v = 0; v < 2; ++v){
    const _Float16* p = Bw + (size_t)(cb + v * 64 + srow) * K + kq;
    rb[v][0] = *(const uint4*)(p);
    rb[v][1] = *(const uint4*)(p + 8);
  }

  const int nt = K >> 6;
  for (int t = 0; t < nt; ++t){
    *(uint4*)&Asm[srow][kq]     = ra[0];
    *(uint4*)&Asm[srow][kq + 8] = ra[1];
    #pragma unroll
    for (int v = 0; v < 2; ++v){
      *(uint4*)&Bsm[v * 64 + srow][kq]     = rb[v][0];
      *(uint4*)&Bsm[v * 64 + srow][kq + 8] = rb[v][1];
    }
    __syncthreads();
    if (t + 1 < nt){
      int kt = (t + 1) << 6;
      if (r0 + srow < n){
        if (A32){
          const float* p = A32 + (size_t)(r0 + srow) * K + kt + kq;
          ra[0] = pack8(*(const float4*)(p),     *(const float4*)(p + 4));
          ra[1] = pack8(*(const float4*)(p + 8), *(const float4*)(p + 12));
        } else {
          const _Float16* p = A16 + (size_t)(r0 + srow) * K + kt + kq;
          ra[0] = *(const uint4*)(p);
          ra[1] = *(const uint4*)(p + 8);
        }
      }
      #pragma unroll
      for (int v = 0; v < 2; ++v){
        const _Float16* p = Bw + (size_t)(cb + v * 64 + srow) * K + kt + kq;
        rb[v][0] = *(const uint4*)(p);
        rb[v][1] = *(const uint4*)(p + 8);
      }
    }
    #pragma unroll
    for (int ks = 0; ks < 2; ++ks){
      const int k0 = ks * 32 + quad * 8;
      h8 a[4], b[2];
      #pragma unroll
      for (int i = 0; i < 4; ++i)
        a[i] = *(const h8*)&Asm[i * 16 + m16][k0];
      #pragma unroll
      for (int j = 0; j < 2; ++j)
        b[j] = *(const h8*)&Bsm[wx * 32 + j * 16 + m16][k0];
      #pragma unroll
      for (int i = 0; i < 4; ++i)
        #pragma unroll
        for (int j = 0; j < 2; ++j)
          acc[i][j] = __builtin_amdgcn_mfma_f32_16x16x32_f16(a[i], b[j], acc[i][j], 0, 0, 0);
    }
    __syncthreads();
  }

  _Float16* Csm = (_Float16*)smem;
  #pragma unroll
  for (int i = 0; i < 4; ++i)
    #pragma unroll
    for (int r = 0; r < 4; ++r){
      int lrow = i * 16 + quad * 4 + r;
      _Float16* cp = Csm + lrow * 136 + wx * 32 + m16;
      #pragma unroll
      for (int j = 0; j < 2; ++j)
        cp[j * 16] = (_Float16)acc[i][j][r];
    }
  __syncthreads();
  #pragma unroll
  for (int v = 0; v < 4; ++v){
    int idx = v * 256 + tid;            // 1024 chunks of 8 f16
    int row = idx >> 4, cx = (idx & 15) * 8;
    if (r0 + row < n)
      *(uint4*)(C + (size_t)(r0 + row) * 256 + cb + cx)
        = *(const uint4*)(Csm + row * 136 + cx);
  }
}

// ---------------- GATv2 aggregation: 16-lane group per node, 8 ch/lane -------
// Gather-latency-bound -> 2-edge unroll + depth-4 rotating prefetch: up to 4
// independent outstanding gathers per lane, 2 independent exp chains/iter.
__global__ __launch_bounds__(256) void agg_wave(
    const _Float16* __restrict__ XLR, const int* __restrict__ col2,
    const int* __restrict__ cnt, const float* __restrict__ att,
    const float* __restrict__ bias, _Float16* __restrict__ H16, int n)
{
  const int lane  = threadIdx.x & 63;
  const int g     = lane >> 4;          // group within wave (0..3)
  const int ll    = lane & 15;
  const int gbase = g << 4;
  const int nl    = ((threadIdx.x >> 6) << 2) + g;   // 0..15
  const int node  = blockIdx.x * 16 + nl;
  if (node >= n) return;
  int deg = cnt[node]; if (deg > CAP) deg = CAP;
  const int c0 = 8 * ll;

  float xr[8], av[8];
  h8tof(*(const uint4*)(XLR + (size_t)node * 256 + 128 + c0), xr);
  #pragma unroll
  for (int i = 0; i < 8; ++i) av[i] = att[c0 + i];

  int s[4];
  #pragma unroll
  for (int q = 0; q < 4; ++q)
    s[q] = (ll + 16 * q < deg) ? col2[(size_t)node * CAP + ll + 16 * q] : 0;

  float l = 0.f, accv[8];
  #pragma unroll
  for (int i = 0; i < 8; ++i) accv[i] = 0.f;

  // depth-4 rotating prefetch (OOB indices clamp to edge 0; deg>=1 self loop)
  uint4 x0, x1, x2, x3;
  {
    int ej0 = bcast4(s, 0, gbase);
    int ej1 = bcast4(s, (1 < deg) ? 1 : 0, gbase);
    int ej2 = bcast4(s, (2 < deg) ? 2 : 0, gbase);
    int ej3 = bcast4(s, (3 < deg) ? 3 : 0, gbase);
    x0 = *(const uint4*)(XLR + (size_t)ej0 * 256 + c0);
    x1 = *(const uint4*)(XLR + (size_t)ej1 * 256 + c0);
    x2 = *(const uint4*)(XLR + (size_t)ej2 * 256 + c0);
    x3 = *(const uint4*)(XLR + (size_t)ej3 * 256 + c0);
  }

  int j = 0;
  for (; j + 2 <= deg; j += 2){
    float c0v[8], c1v[8];
    h8tof(x0, c0v); h8tof(x1, c1v);
    x0 = x2; x1 = x3;
    int ej4 = bcast4(s, (j + 4 < deg) ? j + 4 : 0, gbase);
    int ej5 = bcast4(s, (j + 5 < deg) ? j + 5 : 0, gbase);
    x2 = *(const uint4*)(XLR + (size_t)ej4 * 256 + c0);
    x3 = *(const uint4*)(XLR + (size_t)ej5 * 256 + c0);
    float p0 = 0.f, p1 = 0.f;
    #pragma unroll
    for (int i = 0; i < 8; ++i){
      p0 += lrelu(c0v[i] + xr[i]) * av[i];
      p1 += lrelu(c1v[i] + xr[i]) * av[i];
    }
    p0 += __shfl_xor(p0, 1);  p1 += __shfl_xor(p1, 1);
    p0 += __shfl_xor(p0, 2);  p1 += __shfl_xor(p1, 2);
    float w0 = __expf(p0), w1 = __expf(p1);
    l += w0 + w1;
    #pragma unroll
    for (int i = 0; i < 8; ++i) accv[i] += w0 * c0v[i] + w1 * c1v[i];
  }
  if (j < deg){
    float c0v[8]; h8tof(x0, c0v);
    float p0 = 0.f;
    #pragma unroll
    for (int i = 0; i < 8; ++i) p0 += lrelu(c0v[i] + xr[i]) * av[i];
    p0 += __shfl_xor(p0, 1);
    p0 += __shfl_xor(p0, 2);
    float w0 = __expf(p0);
    l += w0;
    #pragma unroll
    for (int i = 0; i < 8; ++i) accv[i] += w0 * c0v[i];
  }
  float inv = 1.f / l;
  union { h8 h; uint4 u; } o;
  #pragma unroll
  for (int i = 0; i < 8; ++i)
    o.h[i] = (_Float16)(accv[i] * inv + bias[c0 + i]);
  *(uint4*)(H16 + (size_t)node * 128 + c0) = o.u;
}

// ---------------- layer-1 aggregation fused with down_proj -------------------
// Same unrolled/prefetched agg; h staged f32 in LDS; then each thread
// computes 2 (node, o) dot products against LDS-staged dW.
__global__ __launch_bounds__(256) void agg_down(
    const _Float16* __restrict__ XLR, const int* __restrict__ col2,
    const int* __restrict__ cnt, const float* __restrict__ att,
    const float* __restrict__ bias, const float* __restrict__ dW,
    const float* __restrict__ db, float* __restrict__ out, int n)
{
  __shared__ float dwb[32][129];
  __shared__ float hsm[16][128];
  for (int i = threadIdx.x; i < 32 * 128; i += 256)
    dwb[i >> 7][i & 127] = dW[i];

  const int lane  = threadIdx.x & 63;
  const int g     = lane >> 4;
  const int ll    = lane & 15;
  const int gbase = g << 4;
  const int nl    = ((threadIdx.x >> 6) << 2) + g;   // 0..15
  const int node  = blockIdx.x * 16 + nl;
  const bool valid = node < n;
  int deg = 0;
  if (valid){ deg = cnt[node]; if (deg > CAP) deg = CAP; }
  const int c0 = 8 * ll;

  float xr[8], av[8];
  #pragma unroll
  for (int i = 0; i < 8; ++i) xr[i] = 0.f;
  if (valid) h8tof(*(const uint4*)(XLR + (size_t)node * 256 + 128 + c0), xr);
  #pragma unroll
  for (int i = 0; i < 8; ++i) av[i] = att[c0 + i];

  int s[4];
  #pragma unroll
  for (int q = 0; q < 4; ++q)
    s[q] = (valid && ll + 16 * q < deg) ? col2[(size_t)node * CAP + ll + 16 * q] : 0;

  float l = 0.f, accv[8];
  #pragma unroll
  for (int i = 0; i < 8; ++i) accv[i] = 0.f;

  uint4 x0, x1, x2, x3;
  {
    int ej0 = bcast4(s, 0, gbase);
    int ej1 = bcast4(s, (1 < deg) ? 1 : 0, gbase);
    int ej2 = bcast4(s, (2 < deg) ? 2 : 0, gbase);
    int ej3 = bcast4(s, (3 < deg) ? 3 : 0, gbase);
    x0 = *(const uint4*)(XLR + (size_t)ej0 * 256 + c0);
    x1 = *(const uint4*)(XLR + (size_t)ej1 * 256 + c0);
    x2 = *(const uint4*)(XLR + (size_t)ej2 * 256 + c0);
    x3 = *(const uint4*)(XLR + (size_t)ej3 * 256 + c0);
  }

  int j = 0;
  for (; j + 2 <= deg; j += 2){
    float c0v[8], c1v[8];
    h8tof(x0, c0v); h8tof(x1, c1v);
    x0 = x2; x1 = x3;
    int ej4 = bcast4(s, (j + 4 < deg) ? j + 4 : 0, gbase);
    int ej5 = bcast4(s, (j + 5 < deg) ? j + 5 : 0, gbase);
    x2 = *(const uint4*)(XLR + (size_t)ej4 * 256 + c0);
    x3 = *(const uint4*)(XLR + (size_t)ej5 * 256 + c0);
    float p0 = 0.f, p1 = 0.f;
    #pragma unroll
    for (int i = 0; i < 8; ++i){
      p0 += lrelu(c0v[i] + xr[i]) * av[i];
      p1 += lrelu(c1v[i] + xr[i]) * av[i];
    }
    p0 += __shfl_xor(p0, 1);  p1 += __shfl_xor(p1, 1);
    p0 += __shfl_xor(p0, 2);  p1 += __shfl_xor(p1, 2);
    float w0 = __expf(p0), w1 = __expf(p1);
    l += w0 + w1;
    #pragma unroll
    for (int i = 0; i < 8; ++i) accv[i] += w0 * c0v[i] + w1 * c1v[i];
  }
  if (j < deg){
    float c0v[8]; h8tof(x0, c0v);
    float p0 = 0.f;
    #pragma unroll
    for (int i = 0; i < 8; ++i) p0 += lrelu(c0v[i] + xr[i]) * av[i];
    p0 += __shfl_xor(p0, 1);
    p0 += __shfl_xor(p0, 2);
    float w0 = __expf(p0);
    l += w0;
    #pragma unroll
    for (int i = 0; i < 8; ++i) accv[i] += w0 * c0v[i];
  }
  {
    float inv = (deg > 0) ? 1.f / l : 0.f;
    #pragma unroll
    for (int i = 0; i < 8; ++i)
      hsm[nl][c0 + i] = accv[i] * inv + bias[c0 + i];
  }
  __syncthreads();

  // ---- down phase: 512 outputs over 256 threads (2 each) ----
  const int o = threadIdx.x & 31;
  #pragma unroll
  for (int h2 = 0; h2 < 2; ++h2){
    int nl2 = (threadIdx.x >> 5) + h2 * 8;
    int node2 = blockIdx.x * 16 + nl2;
    float sum = 0.f;
    #pragma unroll 8
    for (int k = 0; k < 128; ++k)
      sum += hsm[nl2][k] * dwb[o][k];
    if (node2 < n)
      out[(size_t)node2 * 32 + o] = sum + db[o];
  }
}

extern "C" void kernel_launch(void* const* d_in, const int* in_sizes, int n_in,
                              void* d_out, int out_size, void* d_ws, size_t ws_size,
                              hipStream_t stream) {
  const float* x     = (const float*)d_in[0];
  const int*   ei    = (const int*)  d_in[1];
  const float* Wl0   = (const float*)d_in[2];
  const float* Wr0   = (const float*)d_in[3];
  const float* att0  = (const float*)d_in[4];
  const float* b0    = (const float*)d_in[5];
  const float* Wl1   = (const float*)d_in[6];
  const float* Wr1   = (const float*)d_in[7];
  const float* att1  = (const float*)d_in[8];
  const float* b1    = (const float*)d_in[9];
  const float* dW    = (const float*)d_in[10];
  const float* db    = (const float*)d_in[11];
  float* out = (float*)d_out;

  const int n    = in_sizes[0] / 256;      // 50000
  const int e    = in_sizes[1] / 2;        // 800000
  const int etot = e + n;

  // workspace layout
  _Float16* XLR16 = (_Float16*)d_ws;                    // n*256 f16
  _Float16* H16   = XLR16 + (size_t)n * 256;            // n*128 f16
  int* col2 = (int*)(H16 + (size_t)n * 128);            // n*CAP
  int* cnt  = col2 + (size_t)n * CAP;                   // n
  _Float16* B0h = (_Float16*)(cnt + ((n + 3) & ~3));    // 256*256 f16
  _Float16* B1h = B0h + 65536;                          // 256*128 f16

  (void)hipMemsetAsync(cnt, 0, (size_t)n * sizeof(int), stream);
  build_kernel<<<(etot + 255) / 256, 256, 0, stream>>>(ei, cnt, col2, e, etot);
  convw_kernel<<<96, 256, 0, stream>>>(Wl0, Wr0, Wl1, Wr1, B0h, B1h);

  dim3 ggrid(2, (n + 63) / 64);
  // layer 0 (A = x in f32, fused convert)
  gemm_mfma<<<ggrid, 256, 0, stream>>>(x, nullptr, B0h, XLR16, n, 256);
  agg_wave<<<(n + 15) / 16, 256, 0, stream>>>(XLR16, col2, cnt, att0, b0, H16, n);
  // layer 1 (A = H16 in f16)
  gemm_mfma<<<ggrid, 256, 0, stream>>>(nullptr, H16, B1h, XLR16, n, 128);
  // layer-1 agg + down proj fused
  agg_down<<<(n + 15) / 16, 256, 0, stream>>>(XLR16, col2, cnt, att1, b1, dW, db, out, n);
}